// Round 2
// baseline (11100.873 us; speedup 1.0000x reference)
//
#include <hip/hip_runtime.h>
#include <math.h>

#define BB 64
#define TT 512
#define EE 128
#define HH 256
#define NK 9

#define WROW 386   // padded LDS row stride in doubles (16B aligned, bank-spread)
#define NROWS 32   // gate rows per block (4 gates x 8 units)
#define NB 16      // batch rows per block

// ws byte offsets
#define OFF_TICK  524288ULL                      // hx = 2par*2dir*4bs*4096*8 = 512KB
#define OFF_HS    528384ULL
#define OFF_FEATS (528384ULL + 134217728ULL)     // hs = 2*512*256*64*8

// ---------------- init: hx parity0 from h0, zero counters ----------------
__global__ void init_kernel(double* __restrict__ hx, int* __restrict__ tick,
                            const float* __restrict__ h0) {
  int gid = blockIdx.x * 256 + threadIdx.x;
  if (gid < 2 * HH * BB) {                 // 32768
    int d  = gid >> 14;
    int r  = gid & 16383;
    int bs = r >> 12;
    int bb = (r >> 8) & 15;
    int u  = r & 255;
    // hx layout: [par][dir][bs][bb][u], par=0
    hx[(size_t)(d * 4 + bs) * 4096 + bb * 256 + u] =
        (double)h0[d * 16384 + (bs * 16 + bb) * 256 + u];
  }
  if (gid < 256) tick[gid] = 0;            // 8 counters at stride 32 ints
}

// ---------------- persistent recurrent kernel ----------------
// grid = 256 blocks. group g = bid&7 (dir = g>>2, bslice = g&3) -> all 32 blocks
// of a group land on one XCD (round-robin bid%8 mapping). hslice = bid>>3 owns
// units u0..u0+7. 256 threads: FMA map rr = tid>>4 (rows rr, rr+16), bb = tid&15.
// gate row r (0..31): gate = r>>3, unit = r&7; global row = gate*256 + u0 + unit.
__launch_bounds__(256, 1)
__global__ void recur_kernel(const int* __restrict__ sent, const float* __restrict__ emb,
                             const float* __restrict__ WihF, const float* __restrict__ WhhF,
                             const float* __restrict__ bihF, const float* __restrict__ bhhF,
                             const float* __restrict__ WihB, const float* __restrict__ WhhB,
                             const float* __restrict__ bihB, const float* __restrict__ bhhB,
                             const float* __restrict__ c0,
                             double* __restrict__ hx, int* __restrict__ tick,
                             double* __restrict__ hsout) {
  extern __shared__ double sm[];
  double* wl     = sm;                    // 32 rows x WROW (cols 0..127 Wih, 128..383 Whh)
  double* xh     = sm + NROWS * WROW;     // 16 rows x WROW (cols 0..127 x_t, 128..383 h)
  double* bias_l = xh + NB * WROW;        // 32
  double* g_l    = bias_l + 32;           // 512
  // total doubles = 12352 + 6176 + 32 + 512 = 19072 -> 152576 bytes

  const int tid = threadIdx.x;
  const int g   = blockIdx.x & 7;
  const int dir = g >> 2;
  const int bs  = g & 3;
  const int u0  = (blockIdx.x >> 3) * 8;

  const float* Wih = dir ? WihB : WihF;
  const float* Whh = dir ? WhhB : WhhF;
  const float* bih = dir ? bihB : bihF;
  const float* bhh = dir ? bhhB : bhhF;

  // ---- preload weight slices as f64 ----
  for (int r = 0; r < NROWS; ++r) {
    int grow = (r >> 3) * HH + u0 + (r & 7);
    int c = tid;  // 0..255
    wl[r * WROW + c] = (c < EE) ? (double)Wih[(size_t)grow * EE + c]
                                : (double)Whh[(size_t)grow * HH + (c - EE)];
    if (tid < EE) wl[r * WROW + 256 + tid] = (double)Whh[(size_t)grow * HH + 128 + tid];
  }
  if (tid < NROWS) {
    int grow = (tid >> 3) * HH + u0 + (tid & 7);
    bias_l[tid] = (double)bih[grow] + (double)bhh[grow];
  }
  double creg = 0.0;
  if (tid < 128) {
    int uo = tid >> 4, bb = tid & 15;
    creg = (double)c0[dir * (BB * HH) + (bs * 16 + bb) * HH + u0 + uo];
  }

  // x-staging for a given time index, done by threads 128..255
  auto x_stage = [&](int tq) {
    int t2 = tid - 128;
    int bb = t2 & 15, c = t2 >> 4;       // c 0..7 -> elems c*16 .. c*16+15
    int tok = sent[(bs * 16 + bb) * TT + tq];
    const float4* ep = (const float4*)(emb + (size_t)tok * EE + c * 16);
    double* dst = xh + bb * WROW + c * 16;
    #pragma unroll
    for (int q = 0; q < 4; ++q) {
      float4 v = ep[q];
      dst[q * 4 + 0] = (double)v.x; dst[q * 4 + 1] = (double)v.y;
      dst[q * 4 + 2] = (double)v.z; dst[q * 4 + 3] = (double)v.w;
    }
  };

  const int rr  = tid >> 4;   // 0..15
  const int bbf = tid & 15;
  int* cnt = tick + g * 32;

  if (tid >= 128) x_stage(dir ? TT - 1 : 0);
  __syncthreads();

  for (int i = 0; i < TT; ++i) {
    const int tq = dir ? (TT - 1 - i) : i;

    // ---- wait for group step i ----
    if (tid == 0) {
      const int tgt = 32 * i;
      while (__hip_atomic_load(cnt, __ATOMIC_RELAXED, __HIP_MEMORY_SCOPE_AGENT) < tgt)
        __builtin_amdgcn_s_sleep(1);
    }
    __syncthreads();
    __builtin_amdgcn_fence(__ATOMIC_ACQUIRE, "agent");

    // ---- stage h tile (32KB contiguous) into xh cols 128..383 ----
    const double* hsrc = hx + (size_t)(((i & 1) * 2 + dir) * 4 + bs) * 4096;
    #pragma unroll
    for (int c = 0; c < 8; ++c) {
      int idx = c * 512 + tid * 2;       // 0..4094
      int bb = idx >> 8, u = idx & 255;
      double2 hv = *(const double2*)(hsrc + idx);
      *(double2*)(xh + bb * WROW + EE + u) = hv;
    }
    __syncthreads();

    // ---- unified x+h FMA: 2 rows x 1 batch per thread, b128 reads ----
    double a0 = bias_l[rr], a1 = bias_l[rr + 16];
    const double2* xr = (const double2*)(xh + bbf * WROW);
    const double2* w0 = (const double2*)(wl + rr * WROW);
    const double2* w1 = (const double2*)(wl + (rr + 16) * WROW);
    #pragma unroll 8
    for (int k = 0; k < 192; ++k) {
      double2 v = xr[k], p = w0[k], q = w1[k];
      a0 += v.x * p.x; a0 += v.y * p.y;
      a1 += v.x * q.x; a1 += v.y * q.y;
    }
    g_l[tid] = a0;            // row rr      -> index rr*16+bb = tid
    g_l[tid + 256] = a1;      // row rr+16
    __syncthreads();

    // ---- pointwise cell update (tid<128) || x-stage next step (tid>=128) ----
    if (tid < 128) {
      double iv = g_l[tid], fv = g_l[128 + tid], gv = g_l[256 + tid], ov = g_l[384 + tid];
      double is = 1.0 / (1.0 + exp(-iv));
      double fs = 1.0 / (1.0 + exp(-fv));
      double gs = tanh(gv);
      double os = 1.0 / (1.0 + exp(-ov));
      creg = fs * creg + is * gs;
      double hval = os * tanh(creg);
      int uo = tid >> 4, bb = tid & 15;
      __hip_atomic_store(hx + (size_t)((((i + 1) & 1) * 2 + dir) * 4 + bs) * 4096
                            + bb * 256 + u0 + uo,
                         hval, __ATOMIC_RELAXED, __HIP_MEMORY_SCOPE_AGENT);
      hsout[((size_t)(dir * TT + tq) * HH + u0 + uo) * 64 + bs * 16 + bb] = hval;
    } else if (i + 1 < TT) {
      x_stage(dir ? (TT - 2 - i) : (i + 1));
    }
    __syncthreads();   // drains vmcnt for all waves before signal

    if (tid == 0) {
      __builtin_amdgcn_fence(__ATOMIC_RELEASE, "agent");
      __hip_atomic_fetch_add(cnt, 1, __ATOMIC_RELAXED, __HIP_MEMORY_SCOPE_AGENT);
    }
  }
}

// ---------------- feats = [hf|hb] @ Wout^T + bout ----------------
__global__ void feats_kernel(const double* __restrict__ hs, const float* __restrict__ Wout,
                             const float* __restrict__ bout, double* __restrict__ feats) {
  __shared__ double wl[NK * 2 * HH];   // 4608 doubles
  __shared__ double bl[NK];
  int tid = threadIdx.x, t = blockIdx.x;
  for (int idx = tid; idx < NK * 2 * HH; idx += 256) wl[idx] = (double)Wout[idx];
  if (tid < NK) bl[tid] = (double)bout[tid];
  __syncthreads();
  if (tid < 192) {
    int bb = tid & 63, kg = tid >> 6;   // kg 0..2 -> k = kg*3 + j
    double acc0 = bl[kg * 3 + 0], acc1 = bl[kg * 3 + 1], acc2 = bl[kg * 3 + 2];
    for (int d = 0; d < 2; ++d) {
      const double* hp = hs + ((size_t)(d * TT + t) * HH) * 64 + bb;
      const double* w0 = wl + (kg * 3 + 0) * 2 * HH + d * HH;
      const double* w1 = wl + (kg * 3 + 1) * 2 * HH + d * HH;
      const double* w2 = wl + (kg * 3 + 2) * 2 * HH + d * HH;
      for (int u = 0; u < HH; ++u) {
        double hv = hp[(size_t)u * 64];
        acc0 += hv * w0[u];
        acc1 += hv * w1[u];
        acc2 += hv * w2[u];
      }
    }
    double* fp = feats + ((size_t)bb * TT + t) * NK + kg * 3;
    fp[0] = acc0; fp[1] = acc1; fp[2] = acc2;
  }
}

// ---------------- viterbi decode (one block per batch row) ----------------
__global__ void viterbi_kernel(const double* __restrict__ feats, const float* __restrict__ start,
                               const float* __restrict__ endv, const float* __restrict__ trans,
                               int* __restrict__ out) {
  __shared__ double sc[NK];
  __shared__ double tr[NK * NK];
  __shared__ unsigned char hist[TT - 1][16];
  __shared__ unsigned char tags[TT];
  int lane = threadIdx.x, b = blockIdx.x;
  for (int idx = lane; idx < NK * NK; idx += 64) tr[idx] = (double)trans[idx];
  const double* fb = feats + (size_t)b * TT * NK;
  if (lane < NK) sc[lane] = (double)start[lane] + fb[lane];
  __syncthreads();
  double ftn = (lane < NK) ? fb[NK + lane] : 0.0;
  for (int t = 1; t < TT; ++t) {
    double ft = ftn;
    if (t + 1 < TT && lane < NK) ftn = fb[(size_t)(t + 1) * NK + lane];
    double best = -1e300; int arg = 0;
    if (lane < NK) {
      #pragma unroll
      for (int p = 0; p < NK; ++p) {
        double v = sc[p] + tr[p * NK + lane];
        if (v > best) { best = v; arg = p; }   // strict > keeps first index (jnp.argmax)
      }
      hist[t - 1][lane] = (unsigned char)arg;
    }
    __syncthreads();
    if (lane < NK) sc[lane] = best + ft;   // mask is all-true
    __syncthreads();
  }
  if (lane < NK) sc[lane] += (double)endv[lane];
  __syncthreads();
  if (lane == 0) {
    double best = -1e300; int tag = 0;
    for (int n = 0; n < NK; ++n) if (sc[n] > best) { best = sc[n]; tag = n; }
    tags[TT - 1] = (unsigned char)tag;
    for (int t = TT - 2; t >= 0; --t) { tag = hist[t][tag]; tags[t] = (unsigned char)tag; }
  }
  __syncthreads();
  for (int j = lane; j < TT; j += 64) out[b * TT + j] = (int)tags[j];
}

// ---------------- launcher ----------------
extern "C" void kernel_launch(void* const* d_in, const int* in_sizes, int n_in,
                              void* d_out, int out_size, void* d_ws, size_t ws_size,
                              hipStream_t stream) {
  const int*   sent = (const int*)  d_in[0];
  // d_in[1] = mask (all true) -- unused
  const float* emb  = (const float*)d_in[2];
  const float* WihF = (const float*)d_in[3];
  const float* WhhF = (const float*)d_in[4];
  const float* bihF = (const float*)d_in[5];
  const float* bhhF = (const float*)d_in[6];
  const float* WihB = (const float*)d_in[7];
  const float* WhhB = (const float*)d_in[8];
  const float* bihB = (const float*)d_in[9];
  const float* bhhB = (const float*)d_in[10];
  const float* Wout = (const float*)d_in[11];
  const float* bout = (const float*)d_in[12];
  const float* stv  = (const float*)d_in[13];
  const float* env  = (const float*)d_in[14];
  const float* trv  = (const float*)d_in[15];
  const float* h0   = (const float*)d_in[16];
  const float* c0   = (const float*)d_in[17];

  char* ws = (char*)d_ws;
  double* hx    = (double*)ws;                 // [par][dir][bs][bb][u] f64, 512KB
  int*    tick  = (int*)(ws + OFF_TICK);       // 8 counters, stride 32 ints
  double* hs    = (double*)(ws + OFF_HS);      // [dir][t][u][b64] f64
  double* feats = (double*)(ws + OFF_FEATS);   // [b][t][9] f64
  int* out = (int*)d_out;

  hipFuncSetAttribute((const void*)recur_kernel,
                      hipFuncAttributeMaxDynamicSharedMemorySize, 163840);

  init_kernel<<<128, 256, 0, stream>>>(hx, tick, h0);
  recur_kernel<<<256, 256, 152576, stream>>>(sent, emb, WihF, WhhF, bihF, bhhF,
                                             WihB, WhhB, bihB, bhhB, c0, hx, tick, hs);
  feats_kernel<<<TT, 256, 0, stream>>>(hs, Wout, bout, feats);
  viterbi_kernel<<<BB, 64, 0, stream>>>(feats, stv, env, trv, out);
}

// Round 4
// 3777.430 us; speedup vs baseline: 2.9387x; 2.9387x over previous
//
#include <hip/hip_runtime.h>
#include <math.h>

#define BB 64
#define TT 512
#define EE 128
#define HH 256
#define NK 9

#define WROW 386   // padded LDS row stride in doubles (16B aligned, bank-spread)
#define NROWS 32   // gate rows per block (4 gates x 8 units)
#define NB 16      // batch rows per block

// ws byte offsets
#define OFF_TICK  524288ULL                      // hx = 2par*2dir*4bs*4096*8 = 512KB
#define OFF_HS    528384ULL
#define OFF_FEATS (528384ULL + 134217728ULL)     // hs = 2*512*256*64*8

// ---------------- init: hx parity0 from h0, zero counters ----------------
__global__ void init_kernel(double* __restrict__ hx, int* __restrict__ tick,
                            const float* __restrict__ h0) {
  int gid = blockIdx.x * 256 + threadIdx.x;
  if (gid < 2 * HH * BB) {                 // 32768
    int d  = gid >> 14;
    int r  = gid & 16383;
    int bs = r >> 12;
    int bb = (r >> 8) & 15;
    int u  = r & 255;
    // hx layout: [par][dir][bs][bb][u], par=0
    hx[(size_t)(d * 4 + bs) * 4096 + bb * 256 + u] =
        (double)h0[d * 16384 + (bs * 16 + bb) * 256 + u];
  }
  if (gid < 256) tick[gid] = 0;            // 8 counters at stride 32 ints
}

// ---------------- persistent recurrent kernel ----------------
// grid = 256 blocks. group g = bid&7 (dir = g>>2, bslice = g&3); hslice = bid>>3
// owns units u0..u0+7. All cross-block traffic (h, tickets) uses agent-scope
// relaxed atomics (sc1 -> coherent at L3, independent of XCD mapping). NO
// fences: producer order = sc1 stores + __syncthreads vmcnt drain + sc1 ticket.
__launch_bounds__(256, 1)
__global__ void recur_kernel(const int* __restrict__ sent, const float* __restrict__ emb,
                             const float* __restrict__ WihF, const float* __restrict__ WhhF,
                             const float* __restrict__ bihF, const float* __restrict__ bhhF,
                             const float* __restrict__ WihB, const float* __restrict__ WhhB,
                             const float* __restrict__ bihB, const float* __restrict__ bhhB,
                             const float* __restrict__ c0,
                             double* __restrict__ hx, int* __restrict__ tick,
                             double* __restrict__ hsout) {
  extern __shared__ double sm[];
  double* wl     = sm;                    // 32 rows x WROW (cols 0..127 Wih, 128..383 Whh)
  double* xh     = sm + NROWS * WROW;     // 16 rows x WROW (cols 0..127 x_t, 128..383 h)
  double* bias_l = xh + NB * WROW;        // 32
  double* g_l    = bias_l + 32;           // 512
  // total doubles = 12352 + 6176 + 32 + 512 = 19072 -> 152576 bytes

  const int tid = threadIdx.x;
  const int g   = blockIdx.x & 7;
  const int dir = g >> 2;
  const int bs  = g & 3;
  const int u0  = (blockIdx.x >> 3) * 8;

  const float* Wih = dir ? WihB : WihF;
  const float* Whh = dir ? WhhB : WhhF;
  const float* bih = dir ? bihB : bihF;
  const float* bhh = dir ? bhhB : bhhF;

  // ---- preload weight slices as f64 ----
  for (int r = 0; r < NROWS; ++r) {
    int grow = (r >> 3) * HH + u0 + (r & 7);
    int c = tid;  // 0..255
    wl[r * WROW + c] = (c < EE) ? (double)Wih[(size_t)grow * EE + c]
                                : (double)Whh[(size_t)grow * HH + (c - EE)];
    if (tid < EE) wl[r * WROW + 256 + tid] = (double)Whh[(size_t)grow * HH + 128 + tid];
  }
  if (tid < NROWS) {
    int grow = (tid >> 3) * HH + u0 + (tid & 7);
    bias_l[tid] = (double)bih[grow] + (double)bhh[grow];
  }
  double creg = 0.0;
  if (tid < 128) {
    int uo = tid >> 4, bb = tid & 15;
    creg = (double)c0[dir * (BB * HH) + (bs * 16 + bb) * HH + u0 + uo];
  }

  // x-staging for a given time index, done by threads 128..255
  auto x_stage = [&](int tq) {
    int t2 = tid - 128;
    int bb = t2 & 15, c = t2 >> 4;       // c 0..7 -> elems c*16 .. c*16+15
    int tok = sent[(bs * 16 + bb) * TT + tq];
    const float4* ep = (const float4*)(emb + (size_t)tok * EE + c * 16);
    double* dst = xh + bb * WROW + c * 16;
    #pragma unroll
    for (int q = 0; q < 4; ++q) {
      float4 v = ep[q];
      dst[q * 4 + 0] = (double)v.x; dst[q * 4 + 1] = (double)v.y;
      dst[q * 4 + 2] = (double)v.z; dst[q * 4 + 3] = (double)v.w;
    }
  };

  const int rr  = tid >> 4;   // 0..15
  const int bbf = tid & 15;
  int* cnt = tick + g * 32;

  if (tid >= 128) x_stage(dir ? TT - 1 : 0);
  __syncthreads();

  for (int i = 0; i < TT; ++i) {
    const int tq = dir ? (TT - 1 - i) : i;

    // ---- x-part of gates (k = 0..63 double2) while signals propagate ----
    double a0 = bias_l[rr], a1 = bias_l[rr + 16];
    {
      const double2* xr = (const double2*)(xh + bbf * WROW);
      const double2* w0 = (const double2*)(wl + rr * WROW);
      const double2* w1 = (const double2*)(wl + (rr + 16) * WROW);
      #pragma unroll 8
      for (int k = 0; k < 64; ++k) {
        double2 v = xr[k], p = w0[k], q = w1[k];
        a0 += v.x * p.x; a0 += v.y * p.y;
        a1 += v.x * q.x; a1 += v.y * q.y;
      }
    }

    // ---- wait for group step i (relaxed agent atomic poll, no fence) ----
    if (tid == 0) {
      const int tgt = 32 * i;
      while (__hip_atomic_load(cnt, __ATOMIC_RELAXED, __HIP_MEMORY_SCOPE_AGENT) < tgt) {}
    }
    __syncthreads();

    // ---- stage h tile via agent-scope loads (L3-coherent) into LDS ----
    const double* hsrc = hx + (size_t)(((i & 1) * 2 + dir) * 4 + bs) * 4096;
    {
      double hr[16];
      #pragma unroll
      for (int c = 0; c < 16; ++c)
        hr[c] = __hip_atomic_load(hsrc + c * 256 + tid,
                                  __ATOMIC_RELAXED, __HIP_MEMORY_SCOPE_AGENT);
      #pragma unroll
      for (int c = 0; c < 16; ++c)
        xh[c * WROW + EE + tid] = hr[c];
    }
    __syncthreads();

    // ---- h-part FMA (k = 64..191 double2) ----
    {
      const double2* xr = (const double2*)(xh + bbf * WROW);
      const double2* w0 = (const double2*)(wl + rr * WROW);
      const double2* w1 = (const double2*)(wl + (rr + 16) * WROW);
      #pragma unroll 8
      for (int k = 64; k < 192; ++k) {
        double2 v = xr[k], p = w0[k], q = w1[k];
        a0 += v.x * p.x; a0 += v.y * p.y;
        a1 += v.x * q.x; a1 += v.y * q.y;
      }
    }
    g_l[tid] = a0;            // row rr      -> index rr*16+bb = tid
    g_l[tid + 256] = a1;      // row rr+16
    __syncthreads();

    // ---- pointwise cell update (tid<128) || x-stage next step (tid>=128) ----
    if (tid < 128) {
      double iv = g_l[tid], fv = g_l[128 + tid], gv = g_l[256 + tid], ov = g_l[384 + tid];
      double is = 1.0 / (1.0 + exp(-iv));
      double fs = 1.0 / (1.0 + exp(-fv));
      double gs = tanh(gv);
      double os = 1.0 / (1.0 + exp(-ov));
      creg = fs * creg + is * gs;
      double hval = os * tanh(creg);
      int uo = tid >> 4, bb = tid & 15;
      __hip_atomic_store(hx + (size_t)((((i + 1) & 1) * 2 + dir) * 4 + bs) * 4096
                            + bb * 256 + u0 + uo,
                         hval, __ATOMIC_RELAXED, __HIP_MEMORY_SCOPE_AGENT);
      hsout[((size_t)(dir * TT + tq) * HH + u0 + uo) * 64 + bs * 16 + bb] = hval;
    } else if (i + 1 < TT) {
      x_stage(dir ? (TT - 2 - i) : (i + 1));
    }
    __syncthreads();   // drains vmcnt: h sc1-stores complete at L3 before signal

    if (tid == 0)
      __hip_atomic_fetch_add(cnt, 1, __ATOMIC_RELAXED, __HIP_MEMORY_SCOPE_AGENT);
  }
}

// ---------------- feats = [hf|hb] @ Wout^T + bout ----------------
__global__ void feats_kernel(const double* __restrict__ hs, const float* __restrict__ Wout,
                             const float* __restrict__ bout, double* __restrict__ feats) {
  __shared__ double wl[NK * 2 * HH];   // 4608 doubles
  __shared__ double bl[NK];
  int tid = threadIdx.x, t = blockIdx.x;
  for (int idx = tid; idx < NK * 2 * HH; idx += 256) wl[idx] = (double)Wout[idx];
  if (tid < NK) bl[tid] = (double)bout[tid];
  __syncthreads();
  if (tid < 192) {
    int bb = tid & 63, kg = tid >> 6;   // kg 0..2 -> k = kg*3 + j
    double acc0 = bl[kg * 3 + 0], acc1 = bl[kg * 3 + 1], acc2 = bl[kg * 3 + 2];
    for (int d = 0; d < 2; ++d) {
      const double* hp = hs + ((size_t)(d * TT + t) * HH) * 64 + bb;
      const double* w0 = wl + (kg * 3 + 0) * 2 * HH + d * HH;
      const double* w1 = wl + (kg * 3 + 1) * 2 * HH + d * HH;
      const double* w2 = wl + (kg * 3 + 2) * 2 * HH + d * HH;
      for (int u = 0; u < HH; ++u) {
        double hv = hp[(size_t)u * 64];
        acc0 += hv * w0[u];
        acc1 += hv * w1[u];
        acc2 += hv * w2[u];
      }
    }
    double* fp = feats + ((size_t)bb * TT + t) * NK + kg * 3;
    fp[0] = acc0; fp[1] = acc1; fp[2] = acc2;
  }
}

// ---------------- viterbi decode (one block per batch row) ----------------
__global__ void viterbi_kernel(const double* __restrict__ feats, const float* __restrict__ start,
                               const float* __restrict__ endv, const float* __restrict__ trans,
                               int* __restrict__ out) {
  __shared__ double sc[NK];
  __shared__ double tr[NK * NK];
  __shared__ unsigned char hist[TT - 1][16];
  __shared__ unsigned char tags[TT];
  int lane = threadIdx.x, b = blockIdx.x;
  for (int idx = lane; idx < NK * NK; idx += 64) tr[idx] = (double)trans[idx];
  const double* fb = feats + (size_t)b * TT * NK;
  if (lane < NK) sc[lane] = (double)start[lane] + fb[lane];
  __syncthreads();
  double ftn = (lane < NK) ? fb[NK + lane] : 0.0;
  for (int t = 1; t < TT; ++t) {
    double ft = ftn;
    if (t + 1 < TT && lane < NK) ftn = fb[(size_t)(t + 1) * NK + lane];
    double best = -1e300; int arg = 0;
    if (lane < NK) {
      #pragma unroll
      for (int p = 0; p < NK; ++p) {
        double v = sc[p] + tr[p * NK + lane];
        if (v > best) { best = v; arg = p; }   // strict > keeps first index (jnp.argmax)
      }
      hist[t - 1][lane] = (unsigned char)arg;
    }
    __syncthreads();
    if (lane < NK) sc[lane] = best + ft;   // mask is all-true
    __syncthreads();
  }
  if (lane < NK) sc[lane] += (double)endv[lane];
  __syncthreads();
  if (lane == 0) {
    double best = -1e300; int tag = 0;
    for (int n = 0; n < NK; ++n) if (sc[n] > best) { best = sc[n]; tag = n; }
    tags[TT - 1] = (unsigned char)tag;
    for (int t = TT - 2; t >= 0; --t) { tag = hist[t][tag]; tags[t] = (unsigned char)tag; }
  }
  __syncthreads();
  for (int j = lane; j < TT; j += 64) out[b * TT + j] = (int)tags[j];
}

// ---------------- launcher ----------------
extern "C" void kernel_launch(void* const* d_in, const int* in_sizes, int n_in,
                              void* d_out, int out_size, void* d_ws, size_t ws_size,
                              hipStream_t stream) {
  const int*   sent = (const int*)  d_in[0];
  // d_in[1] = mask (all true) -- unused
  const float* emb  = (const float*)d_in[2];
  const float* WihF = (const float*)d_in[3];
  const float* WhhF = (const float*)d_in[4];
  const float* bihF = (const float*)d_in[5];
  const float* bhhF = (const float*)d_in[6];
  const float* WihB = (const float*)d_in[7];
  const float* WhhB = (const float*)d_in[8];
  const float* bihB = (const float*)d_in[9];
  const float* bhhB = (const float*)d_in[10];
  const float* Wout = (const float*)d_in[11];
  const float* bout = (const float*)d_in[12];
  const float* stv  = (const float*)d_in[13];
  const float* env  = (const float*)d_in[14];
  const float* trv  = (const float*)d_in[15];
  const float* h0   = (const float*)d_in[16];
  const float* c0   = (const float*)d_in[17];

  char* ws = (char*)d_ws;
  double* hx    = (double*)ws;                 // [par][dir][bs][bb][u] f64, 512KB
  int*    tick  = (int*)(ws + OFF_TICK);       // 8 counters, stride 32 ints
  double* hs    = (double*)(ws + OFF_HS);      // [dir][t][u][b64] f64
  double* feats = (double*)(ws + OFF_FEATS);   // [b][t][9] f64
  int* out = (int*)d_out;

  hipFuncSetAttribute((const void*)recur_kernel,
                      hipFuncAttributeMaxDynamicSharedMemorySize, 163840);

  init_kernel<<<128, 256, 0, stream>>>(hx, tick, h0);
  recur_kernel<<<256, 256, 152576, stream>>>(sent, emb, WihF, WhhF, bihF, bhhF,
                                             WihB, WhhB, bihB, bhhB, c0, hx, tick, hs);
  feats_kernel<<<TT, 256, 0, stream>>>(hs, Wout, bout, feats);
  viterbi_kernel<<<BB, 64, 0, stream>>>(feats, stv, env, trv, out);
}